// Round 5
// baseline (903.615 us; speedup 1.0000x reference)
//
#include <hip/hip_runtime.h>

#define T_LEN 1024
#define P_DIM 32
// finfo(f32).min/4 = -(2^126 - 2^102); ulp = 2^102 >> |A|<=0.01, so NEG+A == NEG
// exactly, and NEG < any finite delta. The v=0 slice collapses to one scalar.
#define NEGC (-(3.40282346638528859812e38f / 4.0f))

// packed byte layout: entry (i,p) at ((i>>2)<<7) | (p<<2) | (i&3)
#define PSI_ADDR(i, p) ((((i) >> 2) << 7) | ((p) << 2) | ((i) & 3))

__device__ __forceinline__ float readlane_f(float v, int lane_imm) {
    return __int_as_float(__builtin_amdgcn_readlane(__float_as_int(v), lane_imm));
}

// One wave per batch. p = lane&31 (state); lanes 32-63 are redundant copies
// (harmless — wall time is the 1023-step serial chain).
//
// R5: the carried chain had 3 dependent DS round-trips (~250 cyc each — the
// R2 datum: +2 dependent LDS gathers cost +495 cyc/iter). Replace ALL
// cross-lane traffic in the loop with v_readlane (VALU-speed register
// crossbar, no DS pipe): every lane gets all 32 deltas in-register and runs
// the full 32-candidate (val,idx) tournament locally. Zero DS latency levels
// on the carried chain.
__launch_bounds__(64, 1)
__global__ void crf_viterbi_kernel(const float* __restrict__ U,
                                   const float* __restrict__ A,
                                   const float* __restrict__ bias,
                                   int* __restrict__ out)
{
    __shared__ unsigned char spsi[32768];
    __shared__ unsigned char sj2[32768];
    __shared__ unsigned char sj4[32768];
    __shared__ unsigned char sj8[32768];
    __shared__ unsigned char spath[T_LEN];

    const int b    = blockIdx.x;
    const int lane = threadIdx.x;
    const int p    = lane & 31;
    const int h    = lane >> 5;

    // full A column for this lane's p: A[q][p], q = 0..31
    float Areg[32];
#pragma unroll
    for (int j = 0; j < 32; ++j)
        Areg[j] = A[j * P_DIM + p];
    const float A0p   = Areg[0];  // A[HOME][p]
    const float A00   = A[0];     // A[HOME][HOME]
    const float biasp = bias[p];

    const float* __restrict__ Ub = U + (size_t)b * T_LEN * P_DIM;

    // t = 0
    float u0      = Ub[p] + biasp;
    float delta1  = (p == 0) ? NEGC : u0;     // v=1 slice (register, per-lane p)
    float delta0h = readlane_f(u0, 0);        // v=0 slice lives only at HOME

    // 8-deep unary prefetch — raw values, bias added at consumption
    float ubuf[8];
#pragma unroll
    for (int k = 0; k < 8; ++k)
        ubuf[k] = Ub[(1 + k) * P_DIM + p];

    unsigned int pack = 0;  // psi bytes for 4 consecutive i, flushed as dword

    auto body = [&](int t, int k) {
        const float u_cur = ubuf[k] + biasp;
        int tp = t + 8; if (tp > T_LEN - 1) tp = T_LEN - 1;
        ubuf[k] = Ub[tp * P_DIM + p];       // raw refill, consumed 8 iters later

        // broadcast all 32 deltas via readlane (VALU, no DS pipe), add A column
        float c[32];
#pragma unroll
        for (int j = 0; j < 32; ++j)
            c[j] = readlane_f(delta1, j) + Areg[j];

        // full 32-candidate tournament, first (smallest) index wins ties:
        // right child taken only on strict '>'
        float v16[16]; int i16[16];
#pragma unroll
        for (int j = 0; j < 16; ++j) {
            bool g = c[2 * j + 1] > c[2 * j];
            v16[j] = g ? c[2 * j + 1] : c[2 * j];
            i16[j] = g ? (2 * j + 1) : (2 * j);
        }
        float v8[8]; int i8[8];
#pragma unroll
        for (int j = 0; j < 8; ++j) {
            bool g = v16[2 * j + 1] > v16[2 * j];
            v8[j] = g ? v16[2 * j + 1] : v16[2 * j];
            i8[j] = g ? i16[2 * j + 1] : i16[2 * j];
        }
        float v4[4]; int i4[4];
#pragma unroll
        for (int j = 0; j < 4; ++j) {
            bool g = v8[2 * j + 1] > v8[2 * j];
            v4[j] = g ? v8[2 * j + 1] : v8[2 * j];
            i4[j] = g ? i8[2 * j + 1] : i8[2 * j];
        }
        float v2[2]; int i2[2];
#pragma unroll
        for (int j = 0; j < 2; ++j) {
            bool g = v4[2 * j + 1] > v4[2 * j];
            v2[j] = g ? v4[2 * j + 1] : v4[2 * j];
            i2[j] = g ? i4[2 * j + 1] : i4[2 * j];
        }
        bool  gf = v2[1] > v2[0];
        float v1 = gf ? v2[1] : v2[0];
        int   a1 = gf ? i2[1] : i2[0];

        // v=0 slice: only q=HOME survives (NEG+A==NEG exactly); a0 == 0
        float v0   = delta0h + A0p;
        bool  use1 = v1 > v0;                 // strict, matches reference
        bool  home = (p == 0);
        bool  sel1 = home || use1;
        float sel  = sel1 ? v1 : v0;
        int   p1   = sel1 ? a1 : 0;
        int   vv1  = sel1 ? 1 : 0;
        float dn1  = sel + u_cur;

        float ut0 = readlane_f(u_cur, 0);     // U[t,HOME]+bias[HOME]
        delta0h = (delta0h + A00) + ut0;      // exact reference op order
        delta1  = dn1;

        const int i = t - 1;
        unsigned int psib = (unsigned int)(p1 | (vv1 << 5));
        pack |= psib << (8 * (i & 3));
        if ((i & 3) == 3) {
            if (h == 0)
                *reinterpret_cast<unsigned int*>(&spsi[((i >> 2) << 7) | (p << 2)]) = pack;
            pack = 0;
        }
    };

    // main loop: full groups of 8 (t = 1..1016), then tail t = 1017..1023
    for (int tt = 1; tt + 7 < T_LEN; tt += 8) {
#pragma unroll
        for (int k = 0; k < 8; ++k) body(tt + k, k);
    }
#pragma unroll
    for (int k = 0; k < 7; ++k) body(1017 + k, k);
    // flush partial psi dword (i = 1020..1022, group 255)
    if (h == 0)
        *reinterpret_cast<unsigned int*>(&spsi[(255 << 7) | (p << 2)]) = pack;

    // last_p = argmax_p delta_T[:,1], first index wins
    float mv = delta1;
    int   mi = p;
#pragma unroll
    for (int m = 16; m >= 1; m >>= 1) {
        float ov2 = __shfl_xor(mv, m);
        int   oi2 = __shfl_xor(mi, m);
        bool  tk  = (ov2 > mv) || ((ov2 == mv) && (oi2 < mi));
        mv = tk ? ov2 : mv;
        mi = tk ? oi2 : mi;
    }
    const int last_p = mi;

    // ---- parallel binary-lifting table builds (throughput-bound) ----
    // j2(i,p) = psi(i,p).v ? psi(i-1)[psi(i,p).p] : 0
#pragma unroll 2
    for (int r = 0; r < 512; ++r) {
        int idx = (r << 6) + lane;
        if (idx < 1023 * 32) {
            int i = idx >> 5, pp = idx & 31;
            int bb = spsi[PSI_ADDR(i, pp)];
            int p1 = bb & 31, v = bb >> 5;
            int im = (i >= 1) ? (i - 1) : 0;
            int g  = spsi[PSI_ADDR(im, p1)];
            sj2[PSI_ADDR(i, pp)] = (unsigned char)((v && i >= 1) ? g : 0);
        }
    }
    // j4 = j2 o j2 (shift 2)
#pragma unroll 2
    for (int r = 0; r < 512; ++r) {
        int idx = (r << 6) + lane;
        if (idx < 1023 * 32) {
            int i = idx >> 5, pp = idx & 31;
            int bb = sj2[PSI_ADDR(i, pp)];
            int aa = bb & 31, w = bb >> 5;
            int im = (i >= 2) ? (i - 2) : 0;
            int g  = sj2[PSI_ADDR(im, aa)];
            sj4[PSI_ADDR(i, pp)] = (unsigned char)(w ? g : 0);
        }
    }
    // j8 = j4 o j4 (shift 4)
#pragma unroll 2
    for (int r = 0; r < 512; ++r) {
        int idx = (r << 6) + lane;
        if (idx < 1023 * 32) {
            int i = idx >> 5, pp = idx & 31;
            int bb = sj4[PSI_ADDR(i, pp)];
            int aa = bb & 31, w = bb >> 5;
            int im = (i >= 4) ? (i - 4) : 0;
            int g  = sj4[PSI_ADDR(im, aa)];
            sj8[PSI_ADDR(i, pp)] = (unsigned char)(w ? g : 0);
        }
    }

    // ---- serial chase in 8-step jumps: anchors tau = 1023, 1015, ..., 7 ----
    if (lane == 0) {
        int y = last_p, v = 1;
        spath[T_LEN - 1] = (unsigned char)(y | (v << 5));
        for (int tau = T_LEN - 1; tau >= 15; tau -= 8) {
            int byte = v ? sj8[PSI_ADDR(tau - 1, y)] : 0;
            y = byte & 31; v = byte >> 5;
            spath[tau - 8] = (unsigned char)byte;
        }
    }

    // ---- parallel recovery ----
    // A: anchors tau ≡ 7 (mod 8) -> fill tau-4 (128 entries)
#pragma unroll
    for (int r = 0; r < 2; ++r) {
        int ii  = (r << 6) + lane;
        int tau = 7 + (ii << 3);
        int s   = spath[tau];
        int y   = s & 31, v = s >> 5;
        int byte = v ? sj4[PSI_ADDR(tau - 1, y)] : 0;
        spath[tau - 4] = (unsigned char)byte;
    }
    // B: known tau ≡ 3 (mod 4) -> fill tau-2 (256 entries)
#pragma unroll
    for (int r = 0; r < 4; ++r) {
        int ii  = (r << 6) + lane;
        int tau = 3 + (ii << 2);
        int s   = spath[tau];
        int y   = s & 31, v = s >> 5;
        int byte = v ? sj2[PSI_ADDR(tau - 1, y)] : 0;
        spath[tau - 2] = (unsigned char)byte;
    }
    // C: known odd tau -> fill tau-1 (512 entries)
#pragma unroll
    for (int r = 0; r < 8; ++r) {
        int ii  = (r << 6) + lane;
        int tau = 1 + (ii << 1);
        int s   = spath[tau];
        int y   = s & 31, v = s >> 5;
        int byte = v ? spsi[PSI_ADDR(tau - 1, y)] : 0;
        spath[tau - 1] = (unsigned char)byte;
    }

    // coalesced output
    int* __restrict__ outb = out + (size_t)b * T_LEN;
#pragma unroll
    for (int r = 0; r < 16; ++r) {
        int idx = (r << 6) + lane;
        outb[idx] = spath[idx] & 31;
    }
}

extern "C" void kernel_launch(void* const* d_in, const int* in_sizes, int n_in,
                              void* d_out, int out_size, void* d_ws, size_t ws_size,
                              hipStream_t stream) {
    const float* U    = (const float*)d_in[0];   // (B, T, P) f32
    const float* A    = (const float*)d_in[1];   // (P, P)    f32
    const float* bias = (const float*)d_in[2];   // (P,)      f32
    int* out = (int*)d_out;                      // (B, T)    int32

    const int B = in_sizes[0] / (T_LEN * P_DIM);
    crf_viterbi_kernel<<<B, 64, 0, stream>>>(U, A, bias, out);
}

// Round 6
// 555.870 us; speedup vs baseline: 1.6256x; 1.6256x over previous
//
#include <hip/hip_runtime.h>

#define T_LEN 1024
#define P_DIM 32
// finfo(f32).min/4 = -(2^126 - 2^102); ulp = 2^102 >> |A|<=0.01, so NEG+A == NEG
// exactly, and NEG < any finite delta. The v=0 slice collapses to one scalar.
#define NEGC (-(3.40282346638528859812e38f / 4.0f))

// packed byte layout: entry (i,p) at ((i>>2)<<7) | (p<<2) | (i&3)
#define PSI_ADDR(i, p) ((((i) >> 2) << 7) | ((p) << 2) | ((i) & 3))

__device__ __forceinline__ float bperm_f(int addr, float v) {
    return __int_as_float(__builtin_amdgcn_ds_bpermute(addr, __float_as_int(v)));
}
__device__ __forceinline__ int bperm_i(int addr, int v) {
    return __builtin_amdgcn_ds_bpermute(addr, v);
}

// One wave per batch. Lanes: p = lane&31 (state), h = lane>>5 (half h scans
// predecessors q in [16h,16h+16)). delta1 lives in registers; predecessor
// broadcast via ds_bpermute; argmax off-path via equality mask + ffs (exact
// jnp.argmax first-index semantics).
//
// R6 change vs R4 (body otherwise identical): NO global loads in the forward
// loop. U is staged through LDS in 32-step chunks (double-buffered, 8 KB);
// global float4 loads are issued one full chunk (~10k cyc) before their
// ds_write, and the per-iter unary is a ds_read issued 8 iters ahead.
// Single-wave DS-pipe in-order semantics make write->read correct without
// barriers. This removes the suspected per-iteration vmcnt stall (~500 cyc)
// common to R1-R5.
__launch_bounds__(64, 1)
__global__ void crf_viterbi_kernel(const float* __restrict__ U,
                                   const float* __restrict__ A,
                                   const float* __restrict__ bias,
                                   int* __restrict__ out)
{
    __shared__ unsigned char spsi[32768];
    __shared__ unsigned char sj2[32768];
    __shared__ unsigned char sj4[32768];
    __shared__ unsigned char sj8[32768];
    __shared__ __align__(16) float sbuf[2][32][P_DIM];   // U chunk staging
    __shared__ unsigned char spath[T_LEN];

    const int b     = blockIdx.x;
    const int lane  = threadIdx.x;
    const int p     = lane & 31;
    const int h     = lane >> 5;
    const int hbase = h << 4;
    const int qaddr = hbase << 2;        // byte addr of this half's first source lane
    const int xaddr = (lane ^ 32) << 2;  // cross-half partner
    const int zaddr = 0;                 // lane 0 (home broadcast)

    float Areg[16];
#pragma unroll
    for (int j = 0; j < 16; ++j)
        Areg[j] = A[(hbase + j) * P_DIM + p];
    const float A0p   = A[p];   // A[HOME][p]
    const float A00   = A[0];   // A[HOME][HOME]
    const float biasp = bias[p];

    const float* __restrict__ Ub = U + (size_t)b * T_LEN * P_DIM;

    // ---- prologue staging ----
    // chunk 0 (t=0..31) -> LDS buf[0]; chunk 1 -> stg regs (written at tt=9)
    float4 pre[4];
#pragma unroll
    for (int j = 0; j < 4; ++j)
        pre[j] = *reinterpret_cast<const float4*>(Ub + j * 256 + lane * 4);
    float4 stg[4];
#pragma unroll
    for (int j = 0; j < 4; ++j)
        stg[j] = *reinterpret_cast<const float4*>(Ub + 1024 + j * 256 + lane * 4);
    {
        char* dst = (char*)&sbuf[0][0][0];
#pragma unroll
        for (int j = 0; j < 4; ++j)
            *reinterpret_cast<float4*>(dst + j * 1024 + lane * 16) = pre[j];
    }

    // t = 0
    float u0      = Ub[p] + biasp;
    float delta1  = (p == 0) ? NEGC : u0;   // v=1 slice (register, per-lane p)
    float delta0h = bperm_f(zaddr, u0);     // v=0 slice lives only at HOME

    // 8-deep unary prefetch from LDS (raw; bias added at consumption).
    // ds_reads issued after the ds_writes above: same-wave in-order DS pipe.
    float ureg[8];
#pragma unroll
    for (int k = 0; k < 8; ++k)
        ureg[k] = sbuf[0][1 + k][p];

    unsigned int pack = 0;  // psi bytes for 4 consecutive i, flushed as dword

    auto body = [&](int t, int k) {
        const float u_cur = ureg[k] + biasp;    // fine-grained lgkm wait
        int tp = t + 8; if (tp > T_LEN - 1) tp = T_LEN - 1;
        ureg[k] = sbuf[(tp >> 5) & 1][tp & 31][p];   // independent LDS prefetch

        // 16 independent register broadcasts of delta1[q], q = hbase + j
        float c[16];
#pragma unroll
        for (int j = 0; j < 16; ++j)
            c[j] = bperm_f(qaddr + 4 * j, delta1) + Areg[j];

        // value-only max tree (depth 4), then cross-half max
        float m8[8];
#pragma unroll
        for (int j = 0; j < 8; ++j) m8[j] = fmaxf(c[2 * j], c[2 * j + 1]);
        float m4[4];
#pragma unroll
        for (int j = 0; j < 4; ++j) m4[j] = fmaxf(m8[2 * j], m8[2 * j + 1]);
        float m2a = fmaxf(m4[0], m4[1]);
        float m2b = fmaxf(m4[2], m4[3]);
        float bv  = fmaxf(m2a, m2b);
        float ovv = bperm_f(xaddr, bv);
        float v1  = fmaxf(bv, ovv);

        // argmax off-path: first q with c[q] == v1 (exact jnp.argmax semantics)
        unsigned int msk = 0;
#pragma unroll
        for (int j = 0; j < 16; ++j)
            msk |= (c[j] == v1) ? (1u << j) : 0u;
        int first  = msk ? (hbase + (__ffs(msk) - 1)) : 99;
        int ofirst = bperm_i(xaddr, first);
        int a1     = min(first, ofirst);

        // v=0 slice: only q=HOME survives (NEG+A==NEG exactly); a0 == 0
        float v0   = delta0h + A0p;
        bool  use1 = v1 > v0;                 // strict, matches reference
        bool  home = (p == 0);
        bool  sel1 = home || use1;
        float sel  = sel1 ? v1 : v0;
        int   p1   = sel1 ? a1 : 0;
        int   vv1  = sel1 ? 1 : 0;
        float dn1  = sel + u_cur;

        float ut0 = bperm_f(zaddr, u_cur);    // U[t,HOME]+bias[HOME]
        delta0h = (delta0h + A00) + ut0;      // exact reference op order
        delta1  = dn1;

        const int i = t - 1;
        unsigned int psib = (unsigned int)(p1 | (vv1 << 5));
        pack |= psib << (8 * (i & 3));
        if ((i & 3) == 3) {
            if (h == 0)
                *reinterpret_cast<unsigned int*>(&spsi[((i >> 2) << 7) | (p << 2)]) = pack;
            pack = 0;
        }
    };

    // main loop. Staging block fires at tt = 9 + 32c (inside chunk c):
    //  - writes chunk c+1 (held in stg) into buf[(c+1)&1]; chunk c-1's reads
    //    were all issued by t = 32c-9 (< 32c+9), chunk c+1's first prefetch
    //    read is issued at t = 32c+24 (> 32c+16): ordering safe, in-order pipe.
    //  - loads chunk c+2 into stg (consumed ~32 iters later: vmcnt covered).
    for (int tt = 1; tt + 7 < T_LEN; tt += 8) {
        if ((tt & 31) == 9) {
            const int c  = tt >> 5;
            const int cw = c + 1;
            if (cw < 32) {
                char* dst = (char*)&sbuf[cw & 1][0][0];
#pragma unroll
                for (int j = 0; j < 4; ++j)
                    *reinterpret_cast<float4*>(dst + j * 1024 + lane * 16) = stg[j];
            }
            int cl = c + 2; if (cl > 31) cl = 31;
            const float* src = Ub + cl * 1024;
#pragma unroll
            for (int j = 0; j < 4; ++j)
                stg[j] = *reinterpret_cast<const float4*>(src + j * 256 + lane * 4);
        }
#pragma unroll
        for (int k = 0; k < 8; ++k) body(tt + k, k);
    }
#pragma unroll
    for (int k = 0; k < 7; ++k) body(1017 + k, k);
    // flush partial psi dword (i = 1020..1022, group 255)
    if (h == 0)
        *reinterpret_cast<unsigned int*>(&spsi[(255 << 7) | (p << 2)]) = pack;

    // last_p = argmax_p delta_T[:,1], first index wins
    float mv = delta1;
    int   mi = p;
#pragma unroll
    for (int m = 16; m >= 1; m >>= 1) {
        float ov2 = __shfl_xor(mv, m);
        int   oi2 = __shfl_xor(mi, m);
        bool  tk  = (ov2 > mv) || ((ov2 == mv) && (oi2 < mi));
        mv = tk ? ov2 : mv;
        mi = tk ? oi2 : mi;
    }
    const int last_p = mi;

    // ---- parallel binary-lifting table builds (throughput-bound) ----
    // j2(i,p) = psi(i,p).v ? psi(i-1)[psi(i,p).p] : 0
#pragma unroll 2
    for (int r = 0; r < 512; ++r) {
        int idx = (r << 6) + lane;
        if (idx < 1023 * 32) {
            int i = idx >> 5, pp = idx & 31;
            int bb = spsi[PSI_ADDR(i, pp)];
            int p1 = bb & 31, v = bb >> 5;
            int im = (i >= 1) ? (i - 1) : 0;
            int g  = spsi[PSI_ADDR(im, p1)];
            sj2[PSI_ADDR(i, pp)] = (unsigned char)((v && i >= 1) ? g : 0);
        }
    }
    // j4 = j2 o j2 (shift 2)
#pragma unroll 2
    for (int r = 0; r < 512; ++r) {
        int idx = (r << 6) + lane;
        if (idx < 1023 * 32) {
            int i = idx >> 5, pp = idx & 31;
            int bb = sj2[PSI_ADDR(i, pp)];
            int aa = bb & 31, w = bb >> 5;
            int im = (i >= 2) ? (i - 2) : 0;
            int g  = sj2[PSI_ADDR(im, aa)];
            sj4[PSI_ADDR(i, pp)] = (unsigned char)(w ? g : 0);
        }
    }
    // j8 = j4 o j4 (shift 4)
#pragma unroll 2
    for (int r = 0; r < 512; ++r) {
        int idx = (r << 6) + lane;
        if (idx < 1023 * 32) {
            int i = idx >> 5, pp = idx & 31;
            int bb = sj4[PSI_ADDR(i, pp)];
            int aa = bb & 31, w = bb >> 5;
            int im = (i >= 4) ? (i - 4) : 0;
            int g  = sj4[PSI_ADDR(im, aa)];
            sj8[PSI_ADDR(i, pp)] = (unsigned char)(w ? g : 0);
        }
    }

    // ---- serial chase in 8-step jumps: anchors tau = 1023, 1015, ..., 7 ----
    if (lane == 0) {
        int y = last_p, v = 1;
        spath[T_LEN - 1] = (unsigned char)(y | (v << 5));
        for (int tau = T_LEN - 1; tau >= 15; tau -= 8) {
            int byte = v ? sj8[PSI_ADDR(tau - 1, y)] : 0;
            y = byte & 31; v = byte >> 5;
            spath[tau - 8] = (unsigned char)byte;
        }
    }

    // ---- parallel recovery ----
    // A: anchors tau ≡ 7 (mod 8) -> fill tau-4 (128 entries)
#pragma unroll
    for (int r = 0; r < 2; ++r) {
        int ii  = (r << 6) + lane;
        int tau = 7 + (ii << 3);
        int s   = spath[tau];
        int y   = s & 31, v = s >> 5;
        int byte = v ? sj4[PSI_ADDR(tau - 1, y)] : 0;
        spath[tau - 4] = (unsigned char)byte;
    }
    // B: known tau ≡ 3 (mod 4) -> fill tau-2 (256 entries)
#pragma unroll
    for (int r = 0; r < 4; ++r) {
        int ii  = (r << 6) + lane;
        int tau = 3 + (ii << 2);
        int s   = spath[tau];
        int y   = s & 31, v = s >> 5;
        int byte = v ? sj2[PSI_ADDR(tau - 1, y)] : 0;
        spath[tau - 2] = (unsigned char)byte;
    }
    // C: known odd tau -> fill tau-1 (512 entries)
#pragma unroll
    for (int r = 0; r < 8; ++r) {
        int ii  = (r << 6) + lane;
        int tau = 1 + (ii << 1);
        int s   = spath[tau];
        int y   = s & 31, v = s >> 5;
        int byte = v ? spsi[PSI_ADDR(tau - 1, y)] : 0;
        spath[tau - 1] = (unsigned char)byte;
    }

    // coalesced output
    int* __restrict__ outb = out + (size_t)b * T_LEN;
#pragma unroll
    for (int r = 0; r < 16; ++r) {
        int idx = (r << 6) + lane;
        outb[idx] = spath[idx] & 31;
    }
}

extern "C" void kernel_launch(void* const* d_in, const int* in_sizes, int n_in,
                              void* d_out, int out_size, void* d_ws, size_t ws_size,
                              hipStream_t stream) {
    const float* U    = (const float*)d_in[0];   // (B, T, P) f32
    const float* A    = (const float*)d_in[1];   // (P, P)    f32
    const float* bias = (const float*)d_in[2];   // (P,)      f32
    int* out = (int*)d_out;                      // (B, T)    int32

    const int B = in_sizes[0] / (T_LEN * P_DIM);
    crf_viterbi_kernel<<<B, 64, 0, stream>>>(U, A, bias, out);
}